// Round 15
// baseline (127.934 us; speedup 1.0000x reference)
//
#include <hip/hip_runtime.h>
#include <hip/hip_bf16.h>
#include <stdint.h>

// MultiHeadSelfAttention (b=2,t=2048,m=1024,h=16,d=64), bf16 MFMA pipeline.
//  - reshape head-split => head h = contiguous 131072-elem slab of the per-batch
//    (2048x1024) projection; slab viewed [2048][64]; slab index bb = row>>7.
//  - constant-angle RoPE on q,k cancels exactly in q.k^T => skipped.
//  - K and V stored in a PERMUTED kv order kv' = (col>>6)*128 + (row&127); softmax/PV
//    are permutation-invariant when K and V share the ordering => coalesced VT write.
//  - Q pre-scaled by 0.125*log2(e) so attn softmax runs natively in exp2 domain.
//  - Projections: 128x64 tiles (48KB LDS, 3 blocks/CU); QKV one 1536-block dispatch
//    with V (z==2) transposed via source-swap staging (R13/R14-verified).
//  - attn: MAX-OCCUPANCY split-K. Block = (bh, 64 q-rows), 8 waves = 4 q-waves
//    (16q each) x 2 kv-halves; 32-kv subtiles, dbuf; LDS 40KB -> 4 blocks/CU,
//    grid 1024 -> 32 waves/CU = 8 waves/SIMD. Pair-packed 128B V/P LDS rows.

typedef __attribute__((ext_vector_type(8))) short bf16x8;
typedef bf16x8 __attribute__((may_alias)) bf16x8_a;
typedef __attribute__((ext_vector_type(4))) float f32x4;
typedef f32x4 __attribute__((may_alias)) f32x4_a;
typedef __attribute__((ext_vector_type(2))) unsigned int u32x2;
typedef u32x2 __attribute__((may_alias)) u32x2_a;

__device__ inline unsigned short f2b(float f) {
  union { float f; unsigned int u; } x; x.f = f;
  unsigned int r = x.u + 0x7fffu + ((x.u >> 16) & 1u);  // RTNE
  return (unsigned short)(r >> 16);
}

__device__ inline unsigned cvtpk_bf16(float lo, float hi) {  // dst = {bf16(lo), bf16(hi)}
  unsigned r;
  asm("v_cvt_pk_bf16_f32 %0, %1, %2" : "=v"(r) : "v"(lo), "v"(hi));
  return r;
}

// One fused conversion kernel: blocks [0,4096) -> x, then 1024 blocks per weight.
__global__ __launch_bounds__(256) void cvt_all(
    const float* __restrict__ x,
    const float* __restrict__ w0, const float* __restrict__ w1,
    const float* __restrict__ w2, const float* __restrict__ w3,
    unsigned short* __restrict__ xb,
    unsigned short* __restrict__ o0, unsigned short* __restrict__ o1,
    unsigned short* __restrict__ o2, unsigned short* __restrict__ o3) {
  int bid = blockIdx.x;
  const float* in; unsigned short* out; int i;
  if (bid < 4096) { in = x; out = xb; i = bid * 256 + threadIdx.x; }
  else {
    int w = (bid - 4096) >> 10;
    in = (w == 0) ? w0 : (w == 1) ? w1 : (w == 2) ? w2 : w3;
    out = (w == 0) ? o0 : (w == 1) ? o1 : (w == 2) ? o2 : o3;
    i = ((bid - 4096) & 1023) * 256 + threadIdx.x;
  }
  float4 v = reinterpret_cast<const float4*>(in)[i];
  ushort4 o;
  o.x = f2b(v.x); o.y = f2b(v.y); o.z = f2b(v.z); o.w = f2b(v.w);
  reinterpret_cast<ushort4*>(out)[i] = o;
}

// C(MxN) = A(MxK) @ W(NxK)^T + bias.  128x64 tile, BK=64, 4 waves (each 64x32).
// (unchanged from R14 — verified)
template<int MODE>
__global__ __launch_bounds__(256) void gemm_bt(
    const unsigned short* __restrict__ A,
    const unsigned short* __restrict__ W0, const unsigned short* __restrict__ W1,
    const unsigned short* __restrict__ W2,
    const float* __restrict__ b0, const float* __restrict__ b1, const float* __restrict__ b2,
    unsigned short* __restrict__ o0, unsigned short* __restrict__ o1,
    unsigned short* __restrict__ o2,
    float* __restrict__ of, int M, int N, int K)
{
  const int tid = threadIdx.x;
  const int lane = tid & 63;
  const int wid = tid >> 6;
  const int q4 = lane >> 4;
  const int l15 = lane & 15;
  const int wr = wid >> 1, wc = wid & 1;

  const unsigned short* W = W0; const float* bias = b0; unsigned short* ob = o0;
  if (MODE == 0) {
    if (blockIdx.z == 1) { W = W1; bias = b1; ob = o1; }
    else if (blockIdx.z == 2) { W = W2; bias = b2; ob = o2; }
  }
  const bool vsw = (MODE == 0) && (blockIdx.z == 2);   // scalar, once

  __shared__ __align__(16) unsigned short sA[2][128 * 64];   // 16 KB per buffer
  __shared__ __align__(16) unsigned short sB[2][64 * 64];    //  8 KB per buffer
  char* sAc = (char*)sA;
  char* sBc = (char*)sB;

  f32x4 acc[4][2];
#pragma unroll
  for (int i = 0; i < 4; ++i)
#pragma unroll
    for (int j = 0; j < 2; ++j) acc[i][j] = (f32x4){0.f, 0.f, 0.f, 0.f};

  const size_t rowA0 = (size_t)blockIdx.x * 128;   // non-vsw A rows
  const size_t rowB0 = (size_t)blockIdx.y * 64;    // non-vsw W rows (out cols)
  // vsw grid remap: 8 W-tiles (128 rows) x 64 x-tiles (64 rows) == 32x16 grid
  const int wt = (int)(blockIdx.y >> 1);
  const int xt = (int)(blockIdx.x * 2 + (blockIdx.y & 1));

  const unsigned short* srcA0 = vsw ? (W + (size_t)wt * 128 * K) : (A + rowA0 * K);
  const unsigned short* srcB0 = vsw ? (A + (size_t)xt * 64 * K) : (W + rowB0 * K);

  auto stage = [&](int bs, int k0) {
#pragma unroll
    for (int it = 0; it < 4; ++it) {              // sA: 128 rows
      int Loff = it * 4096 + wid * 1024;          // wave-uniform LDS byte base
      int L = Loff + lane * 16;                   // linear LDS byte this lane fills
      int row = L >> 7;                           // tile row (128B per row)
      int csrc = ((L >> 4) & 7) ^ (row & 7);      // inverse-swizzled source chunk
      const unsigned short* ga = srcA0 + (size_t)row * K + k0 + csrc * 8;
      __builtin_amdgcn_global_load_lds((const __attribute__((address_space(1))) void*)ga,
                                       (__attribute__((address_space(3))) void*)(sAc + bs * 16384 + Loff),
                                       16, 0, 0);
    }
#pragma unroll
    for (int it = 0; it < 2; ++it) {              // sB: 64 rows
      int Loff = it * 4096 + wid * 1024;
      int L = Loff + lane * 16;
      int row = L >> 7;
      int csrc = ((L >> 4) & 7) ^ (row & 7);
      const unsigned short* gw = srcB0 + (size_t)row * K + k0 + csrc * 8;
      __builtin_amdgcn_global_load_lds((const __attribute__((address_space(1))) void*)gw,
                                       (__attribute__((address_space(3))) void*)(sBc + bs * 8192 + Loff),
                                       16, 0, 0);
    }
  };

  stage(0, 0);

  const int NT = K >> 6;
  for (int t = 0; t < NT; ++t) {
    const int cur = t & 1;
    __syncthreads();                 // drains tile t's loads; buf cur^1 reads done
    if (t + 1 < NT) stage(cur ^ 1, (t + 1) * 64);   // flies under compute(t)

#pragma unroll
    for (int ks = 0; ks < 2; ++ks) {
      bf16x8 af[4], bfr[2];
#pragma unroll
      for (int f = 0; f < 4; ++f) {
        int ra = wr * 64 + f * 16 + l15;
        af[f] = *(const bf16x8_a*)(sAc + cur * 16384 + ra * 128 +
                                   ((ks * 64 + q4 * 16) ^ ((ra & 7) << 4)));
      }
#pragma unroll
      for (int f = 0; f < 2; ++f) {
        int rb = wc * 32 + f * 16 + l15;
        bfr[f] = *(const bf16x8_a*)(sBc + cur * 8192 + rb * 128 +
                                    ((ks * 64 + q4 * 16) ^ ((rb & 7) << 4)));
      }
      __builtin_amdgcn_s_setprio(1);
#pragma unroll
      for (int i = 0; i < 4; ++i)
#pragma unroll
        for (int j = 0; j < 2; ++j)
          acc[i][j] = __builtin_amdgcn_mfma_f32_16x16x32_bf16(af[i], bfr[j], acc[i][j], 0, 0, 0);
      __builtin_amdgcn_s_setprio(0);
    }
  }

  if (MODE == 0 && blockIdx.z == 2) {
    // source-swapped: acc[i][j][r] = V^T value at
    //   n (W row / out col) = wt*128 + wr*64 + i*16 + q4*4 + r
    //   x row               = xt*64 + wc*32 + j*16 + l15
    const int bb = xt >> 1;                        // head slab index b*16+h
    const int sbase = (xt & 1) * 64;               // slab-row base (x row & 127)
#pragma unroll
    for (int i = 0; i < 4; ++i) {
      const int nb = wt * 128 + wr * 64 + i * 16 + q4 * 4;
#pragma unroll
      for (int j = 0; j < 2; ++j) {
        const int srow = sbase + wc * 32 + j * 16 + l15;
#pragma unroll
        for (int r = 0; r < 4; ++r) {
          const int n = nb + r;
          ob[(size_t)bb * 131072 + (size_t)(n & 63) * 2048 +
             (size_t)(n >> 6) * 128 + srow] = f2b(acc[i][j][r] + bias[n]);
        }
      }
    }
  } else {
#pragma unroll
    for (int i = 0; i < 4; ++i) {
      int row = (int)rowA0 + wr * 64 + i * 16 + q4 * 4;
#pragma unroll
      for (int j = 0; j < 2; ++j) {
        int col = (int)rowB0 + wc * 32 + j * 16 + l15;
        float bv = bias[col];
        if (MODE == 0 && blockIdx.z == 1) {
          // K, kv'-permuted: addr = bb*131072 + ((col>>6)*128 + (row&127))*64 + d
#pragma unroll
          for (int r = 0; r < 4; ++r) {
            size_t a = (size_t)((row + r) >> 7) * 131072 +
                       (size_t)(((col >> 6) << 7) + ((row + r) & 127)) * 64 + (col & 63);
            ob[a] = f2b(acc[i][j][r] + bv);
          }
        } else {
#pragma unroll
          for (int r = 0; r < 4; ++r) {
            float v = acc[i][j][r] + bv;
            if (MODE == 0) ob[(size_t)(row + r) * N + col] = f2b(v * 0.18033688f);  // Q: 0.125*log2e
            else           of[(size_t)(row + r) * N + col] = v;
          }
        }
      }
    }
  }
}

// Flash attention, swapped-QK^T, max-occupancy split-K.
// Block = 512 thr (8 waves) covering 64 q-rows: 4 q-waves (16q each) x 2 kv
// halves. kv subtile = 32, dbuf K/VT in LDS, 1 barrier/iter. LDS 40KB ->
// 4 blocks/CU; grid 1024 -> 32 waves/CU = 8 waves/SIMD (max).
// Pair-packed 128B V/P LDS rows (2-way bank free). exp2 softmax, defer-max.
__global__ __launch_bounds__(512, 8) void attn_kernel(
    const unsigned short* __restrict__ Qg,
    const unsigned short* __restrict__ Kg,
    const unsigned short* __restrict__ VTg,
    unsigned short* __restrict__ ctx)
{
  const int tid = threadIdx.x;
  const int lane = tid & 63;
  const int wid = tid >> 6;          // 0..7
  const int half = wid >> 2;         // kv half
  const int wq = wid & 3;            // q-wave within half (16 q-rows each)
  const int q4 = lane >> 4;
  const int l15 = lane & 15;

  // XCD-aware decode: xcd = bid&7 owns 4 whole heads -> K/VT L2-resident.
  const int bid = blockIdx.x;        // 1024 blocks
  const int r7 = bid >> 3;           // 0..127
  const int bh = (bid & 7) * 4 + (r7 >> 5);
  const int qt = r7 & 31;            // 32 q-tiles of 64 rows
  const int b = bh >> 4, h = bh & 15;
  const size_t base = (size_t)bh * 131072;
  const unsigned short* Qh = Qg + base;
  const unsigned short* Kh = Kg + base;
  const unsigned short* VTh = VTg + base;
  const int q0 = qt * 64;
  const int kvbase = half * 1024;

  // smem: [0,16384) sK[half][dbuf][32kv x 128B]; [16384,32768) sV (pair-packed);
  // [32768,40960) sP[wid][8 x 128B pair-packed q rows]. Merge reuses [0,*).
  __shared__ __align__(16) char smem[40960];
  char* sKc = smem;
  char* sVc = smem + 16384;
  char* sPw = smem + 32768 + wid * 1024;

  // Q fragment: rows = q0 + wq*16 + l15 (same rows in both halves)
  bf16x8 qf[2];
#pragma unroll
  for (int ks = 0; ks < 2; ++ks)
    qf[ks] = *(const bf16x8*)(Qh + (size_t)(q0 + wq * 16 + l15) * 64 + ks * 32 + q4 * 8);

  // staging sources (per-lane pre-swizzled; global_load_lds dest is linear).
  const int u = tid & 255;                            // within-half thread index
  const int rK = u >> 3;                              // 0..31 kv row
  const int cK = ((u & 7) ^ (rK & 7)) * 8;
  const unsigned short* gK = Kh + (size_t)(kvbase + rK) * 64 + cK;
  const int rV = u >> 3;                              // 0..31 LDS row
  const int cV = (u & 7) ^ (rV & 7);                  // logical chunk
  const int dV = rV * 2 + (cV >> 2);
  const unsigned short* gV = VTh + (size_t)dV * 2048 + kvbase + (cV & 3) * 8;

  auto stage = [&](int bs, int t) {                   // t = tile idx within half
    char* dK = sKc + half * 8192 + bs * 4096 + wq * 1024;
    char* dV_ = sVc + half * 8192 + bs * 4096 + wq * 1024;
    __builtin_amdgcn_global_load_lds(
        (const __attribute__((address_space(1))) void*)(gK + (size_t)t * 2048),
        (__attribute__((address_space(3))) void*)dK, 16, 0, 0);
    __builtin_amdgcn_global_load_lds(
        (const __attribute__((address_space(1))) void*)(gV + t * 32),
        (__attribute__((address_space(3))) void*)dV_, 16, 0, 0);
  };

  const int vp_chunk = (((l15 & 1) * 4 + q4) ^ ((l15 >> 1) & 7)) * 16;
  const int vp_row = (l15 >> 1) * 128;

  f32x4 oacc[4];                       // O[q=q4*4+r][d=fn*16+l15]
#pragma unroll
  for (int fn = 0; fn < 4; ++fn) oacc[fn] = (f32x4){0.f, 0.f, 0.f, 0.f};
  float m_run = -INFINITY, l_run = 0.f;  // log2-domain state for q-row = l15

  stage(0, 0);

  for (int t = 0; t < 32; ++t) {
    const int cur = t & 1;
    __syncthreads();                   // drains vmcnt: tile t staged; buf cur^1 free
    if (t < 31) stage(cur ^ 1, t + 1);

    char* kbuf = sKc + half * 8192 + cur * 4096;
    char* vbuf = sVc + half * 8192 + cur * 4096;

    // ---- S^T = K Q^T : sc[fm][r] = S_log2[kv=fm*16+q4*4+r][q=l15]
    f32x4 sc[2];
#pragma unroll
    for (int fm = 0; fm < 2; ++fm) sc[fm] = (f32x4){0.f, 0.f, 0.f, 0.f};
    __builtin_amdgcn_s_setprio(1);
#pragma unroll
    for (int ks = 0; ks < 2; ++ks) {
#pragma unroll
      for (int fm = 0; fm < 2; ++fm) {
        const int rk = fm * 16 + l15;
        bf16x8_a kf = *(const bf16x8_a*)(kbuf + rk * 128 +
                                         ((ks * 64 + q4 * 16) ^ ((rk & 7) << 4)));
        sc[fm] = __builtin_amdgcn_mfma_f32_16x16x32_bf16(kf, qf[ks], sc[fm], 0, 0, 0);
      }
    }
    __builtin_amdgcn_s_setprio(0);

    // ---- online softmax (exp2 domain, defer-max); 8 vals/lane
    float mx = fmaxf(fmaxf(fmaxf(sc[0][0], sc[0][1]), fmaxf(sc[0][2], sc[0][3])),
                     fmaxf(fmaxf(sc[1][0], sc[1][1]), fmaxf(sc[1][2], sc[1][3])));
    mx = fmaxf(mx, __shfl_xor(mx, 16));
    mx = fmaxf(mx, __shfl_xor(mx, 32));
    if (!__all(mx <= m_run + 11.54f)) {    // wave-uniform rescale path
      const float mnew = fmaxf(m_run, mx);
      const float sc_o = __builtin_amdgcn_exp2f(m_run - mnew);   // -inf on t=0 -> 0
      l_run *= sc_o;
      m_run = mnew;
#pragma unroll
      for (int r = 0; r < 4; ++r) {
        const float so = __shfl(sc_o, (lane & 48) | (q4 * 4 + r));
#pragma unroll
        for (int fn = 0; fn < 4; ++fn) oacc[fn][r] *= so;
      }
    }
    float rs = 0.f;
#pragma unroll
    for (int fm = 0; fm < 2; ++fm)
#pragma unroll
      for (int r = 0; r < 4; ++r) {
        sc[fm][r] = __builtin_amdgcn_exp2f(sc[fm][r] - m_run);   // <= 2^11.54
        rs += sc[fm][r];
      }
    rs += __shfl_xor(rs, 16);
    rs += __shfl_xor(rs, 32);
    l_run += rs;

    // pack P -> pair-packed sP: q=l15 -> row (l15>>1), 128B rows;
    // logical chunk = (q&1)*4 + fm*2 + (q4>>1), stored chunk ^= row&7.
    {
      char* rowp = sPw + (l15 >> 1) * 128;
      const int wbase = ((l15 & 1) * 4 + (q4 >> 1)) ^ ((l15 >> 1) & 7);
#pragma unroll
      for (int fm = 0; fm < 2; ++fm) {
        u32x2 pk;
        pk[0] = cvtpk_bf16(sc[fm][0], sc[fm][1]);
        pk[1] = cvtpk_bf16(sc[fm][2], sc[fm][3]);
        *(u32x2_a*)(rowp + ((wbase ^ (fm * 2)) << 4) + (q4 & 1) * 8) = pk;
      }
    }
    // fence: cross-lane LDS exchange within the wave (writes above, reads below)
    asm volatile("s_waitcnt lgkmcnt(0)" ::: "memory");
    __builtin_amdgcn_sched_barrier(0);

    // ---- O += P V : A from sP, B = VT rows; both pair-packed (2-way banks)
    bf16x8 pf = *(const bf16x8_a*)(sPw + vp_row + vp_chunk);
    __builtin_amdgcn_s_setprio(1);
#pragma unroll
    for (int fn = 0; fn < 4; ++fn) {
      bf16x8_a vf = *(const bf16x8_a*)(vbuf + fn * 1024 + vp_row + vp_chunk);
      oacc[fn] = __builtin_amdgcn_mfma_f32_16x16x32_bf16(pf, vf, oacc[fn], 0, 0, 0);
    }
    __builtin_amdgcn_s_setprio(0);
  }

  // ---- split-K merge: half 1 dumps O/m/l; half 0 flash-combines + stores
  __syncthreads();                     // all compute done; smem reusable
  if (half == 1) {
    char* mb = smem + wq * 4096;
#pragma unroll
    for (int fn = 0; fn < 4; ++fn)
      *(f32x4_a*)(mb + (fn * 64 + lane) * 16) = oacc[fn];
    if (q4 == 0)
      *(float2*)(smem + 16384 + (wq * 16 + l15) * 8) = make_float2(m_run, l_run);
  }
  __syncthreads();
  if (half == 0) {
    char* mb = smem + wq * 4096;
    float2 ml = *(const float2*)(smem + 16384 + (wq * 16 + l15) * 8);
    const float mm = fmaxf(m_run, ml.x);
    const float w1 = __builtin_amdgcn_exp2f(m_run - mm);
    const float w2 = __builtin_amdgcn_exp2f(ml.x - mm);
    const float li = 1.0f / (l_run * w1 + ml.y * w2);
#pragma unroll
    for (int r = 0; r < 4; ++r) {
      const int src = (lane & 48) | (q4 * 4 + r);
      const float w1b = __shfl(w1, src);
      const float w2b = __shfl(w2, src);
      const float lib = __shfl(li, src);
      const int trow = q0 + wq * 16 + q4 * 4 + r;
      const size_t ro = ((size_t)b * 2048 + trow) * 1024 + h * 64;
#pragma unroll
      for (int fn = 0; fn < 4; ++fn) {
        f32x4 o2 = *(const f32x4_a*)(mb + (fn * 64 + lane) * 16);
        ctx[ro + fn * 16 + l15] = f2b((oacc[fn][r] * w1b + o2[r] * w2b) * lib);
      }
    }
  }
}

extern "C" void kernel_launch(void* const* d_in, const int* in_sizes, int n_in,
                              void* d_out, int out_size, void* d_ws, size_t ws_size,
                              hipStream_t stream) {
  const float* x  = (const float*)d_in[0];
  const float* wq = (const float*)d_in[1];
  const float* bq = (const float*)d_in[2];
  const float* wk = (const float*)d_in[3];
  const float* bk = (const float*)d_in[4];
  const float* wv = (const float*)d_in[5];
  const float* bv = (const float*)d_in[6];
  const float* wo = (const float*)d_in[7];
  const float* bo = (const float*)d_in[8];
  // d_in[9]/d_in[10] (rot tables) unused: constant-angle RoPE cancels in q.k^T.

  char* ws = (char*)d_ws;
  unsigned short* xb  = (unsigned short*)(ws);               // 8 MB (reused as ctx)
  unsigned short* wqb = (unsigned short*)(ws + 8388608);
  unsigned short* wkb = (unsigned short*)(ws + 10485760);
  unsigned short* wvb = (unsigned short*)(ws + 12582912);
  unsigned short* wob = (unsigned short*)(ws + 14680064);
  unsigned short* Qb  = (unsigned short*)(ws + 16777216);    // 8 MB
  unsigned short* Kb  = (unsigned short*)(ws + 25165824);    // 8 MB, kv'-permuted
  unsigned short* VTb = (unsigned short*)(ws + 33554432);    // 8 MB, [bh][d][kv']
  unsigned short* ctx = xb;  // x dead after QKV projection

  cvt_all<<<8192, 256, 0, stream>>>(x, wq, wk, wv, wo, xb, wqb, wkb, wvb, wob);

  gemm_bt<0><<<dim3(32, 16, 3), 256, 0, stream>>>(
      xb, wqb, wkb, wvb, bq, bk, bv, Qb, Kb, VTb, nullptr, 4096, 1024, 1024);

  attn_kernel<<<dim3(1024), dim3(512), 0, stream>>>(Qb, Kb, VTb, ctx);

  gemm_bt<1><<<dim3(32, 16, 1), 256, 0, stream>>>(
      ctx, wob, nullptr, nullptr, bo, nullptr, nullptr, nullptr, nullptr, nullptr,
      (float*)d_out, 4096, 1024, 1024);
}

// Round 16
// 119.087 us; speedup vs baseline: 1.0743x; 1.0743x over previous
//
#include <hip/hip_runtime.h>
#include <hip/hip_bf16.h>
#include <stdint.h>

// MultiHeadSelfAttention (b=2,t=2048,m=1024,h=16,d=64), bf16 MFMA pipeline.
// === R14 configuration (verified best: 119.1us) ===
//  - reshape head-split => head h = contiguous 131072-elem slab of the per-batch
//    (2048x1024) projection; slab viewed [2048][64]; slab index bb = row>>7.
//  - constant-angle RoPE on q,k cancels exactly in q.k^T => skipped.
//  - K and V stored in a PERMUTED kv order kv' = (col>>6)*128 + (row&127); softmax/PV
//    are permutation-invariant when K and V share the ordering => coalesced VT write.
//  - Q pre-scaled by 0.125*log2(e) so attn softmax runs natively in exp2 domain.
//  - Projections: 128x64 tiles (48KB LDS -> 3 blocks/CU); QKV one 1536-block
//    dispatch with V (z==2) transposed via source-swap staging.
//  - attn: in-block SPLIT-K (8 waves = 4 q-waves x 2 kv-halves, 32q/wave),
//    32-kv subtiles, dbuf, pair-packed 128B V/P LDS rows (2-way bank free),
//    exp2-domain softmax with defer-max, flash-combine merge through LDS.
//  Geometry search concluded: {1-wave, 4wx32q, 8wx32q-splitK, 8wx16q-splitK}
//  => 8wx32q-splitK is the optimum; further gains need cross-wave counted-vmcnt
//  role-split (race-prone), out of scope.

typedef __attribute__((ext_vector_type(8))) short bf16x8;
typedef bf16x8 __attribute__((may_alias)) bf16x8_a;
typedef __attribute__((ext_vector_type(4))) float f32x4;
typedef f32x4 __attribute__((may_alias)) f32x4_a;
typedef __attribute__((ext_vector_type(2))) unsigned int u32x2;
typedef u32x2 __attribute__((may_alias)) u32x2_a;

__device__ inline unsigned short f2b(float f) {
  union { float f; unsigned int u; } x; x.f = f;
  unsigned int r = x.u + 0x7fffu + ((x.u >> 16) & 1u);  // RTNE
  return (unsigned short)(r >> 16);
}

__device__ inline unsigned cvtpk_bf16(float lo, float hi) {  // dst = {bf16(lo), bf16(hi)}
  unsigned r;
  asm("v_cvt_pk_bf16_f32 %0, %1, %2" : "=v"(r) : "v"(lo), "v"(hi));
  return r;
}

// One fused conversion kernel: blocks [0,4096) -> x, then 1024 blocks per weight.
__global__ __launch_bounds__(256) void cvt_all(
    const float* __restrict__ x,
    const float* __restrict__ w0, const float* __restrict__ w1,
    const float* __restrict__ w2, const float* __restrict__ w3,
    unsigned short* __restrict__ xb,
    unsigned short* __restrict__ o0, unsigned short* __restrict__ o1,
    unsigned short* __restrict__ o2, unsigned short* __restrict__ o3) {
  int bid = blockIdx.x;
  const float* in; unsigned short* out; int i;
  if (bid < 4096) { in = x; out = xb; i = bid * 256 + threadIdx.x; }
  else {
    int w = (bid - 4096) >> 10;
    in = (w == 0) ? w0 : (w == 1) ? w1 : (w == 2) ? w2 : w3;
    out = (w == 0) ? o0 : (w == 1) ? o1 : (w == 2) ? o2 : o3;
    i = ((bid - 4096) & 1023) * 256 + threadIdx.x;
  }
  float4 v = reinterpret_cast<const float4*>(in)[i];
  ushort4 o;
  o.x = f2b(v.x); o.y = f2b(v.y); o.z = f2b(v.z); o.w = f2b(v.w);
  reinterpret_cast<ushort4*>(out)[i] = o;
}

// C(MxN) = A(MxK) @ W(NxK)^T + bias.  128x64 tile, BK=64, 4 waves (each 64x32).
// 2-phase pipeline: dbuf LDS; per K-step {sync; stage(next->buf^1); compute(cur)}.
// MODE 0: z=0 -> Q bf16 row-major, pre-scaled by 0.125*log2e;
//         z=1 -> K bf16, kv'-permuted: addr = bb*131072 + kv'*64 + d;
//         z=2 -> V transposed via SOURCE-SWAP staging (W 128-row tile -> sA,
//                x 64-row tile -> sB; grid remapped wt=y>>1, xt=x*2+(y&1));
//                writes VT'[bb][d][kv'], coalesced 32B runs.
// MODE 1: fp32 output (final projection), row-major.
template<int MODE>
__global__ __launch_bounds__(256) void gemm_bt(
    const unsigned short* __restrict__ A,
    const unsigned short* __restrict__ W0, const unsigned short* __restrict__ W1,
    const unsigned short* __restrict__ W2,
    const float* __restrict__ b0, const float* __restrict__ b1, const float* __restrict__ b2,
    unsigned short* __restrict__ o0, unsigned short* __restrict__ o1,
    unsigned short* __restrict__ o2,
    float* __restrict__ of, int M, int N, int K)
{
  const int tid = threadIdx.x;
  const int lane = tid & 63;
  const int wid = tid >> 6;
  const int q4 = lane >> 4;
  const int l15 = lane & 15;
  const int wr = wid >> 1, wc = wid & 1;

  const unsigned short* W = W0; const float* bias = b0; unsigned short* ob = o0;
  if (MODE == 0) {
    if (blockIdx.z == 1) { W = W1; bias = b1; ob = o1; }
    else if (blockIdx.z == 2) { W = W2; bias = b2; ob = o2; }
  }
  const bool vsw = (MODE == 0) && (blockIdx.z == 2);   // scalar, once

  __shared__ __align__(16) unsigned short sA[2][128 * 64];   // 16 KB per buffer
  __shared__ __align__(16) unsigned short sB[2][64 * 64];    //  8 KB per buffer
  char* sAc = (char*)sA;
  char* sBc = (char*)sB;

  f32x4 acc[4][2];
#pragma unroll
  for (int i = 0; i < 4; ++i)
#pragma unroll
    for (int j = 0; j < 2; ++j) acc[i][j] = (f32x4){0.f, 0.f, 0.f, 0.f};

  const size_t rowA0 = (size_t)blockIdx.x * 128;   // non-vsw A rows
  const size_t rowB0 = (size_t)blockIdx.y * 64;    // non-vsw W rows (out cols)
  // vsw grid remap: 8 W-tiles (128 rows) x 64 x-tiles (64 rows) == 32x16 grid
  const int wt = (int)(blockIdx.y >> 1);
  const int xt = (int)(blockIdx.x * 2 + (blockIdx.y & 1));

  const unsigned short* srcA0 = vsw ? (W + (size_t)wt * 128 * K) : (A + rowA0 * K);
  const unsigned short* srcB0 = vsw ? (A + (size_t)xt * 64 * K) : (W + rowB0 * K);

  auto stage = [&](int bs, int k0) {
#pragma unroll
    for (int it = 0; it < 4; ++it) {              // sA: 128 rows
      int Loff = it * 4096 + wid * 1024;          // wave-uniform LDS byte base
      int L = Loff + lane * 16;                   // linear LDS byte this lane fills
      int row = L >> 7;                           // tile row (128B per row)
      int csrc = ((L >> 4) & 7) ^ (row & 7);      // inverse-swizzled source chunk
      const unsigned short* ga = srcA0 + (size_t)row * K + k0 + csrc * 8;
      __builtin_amdgcn_global_load_lds((const __attribute__((address_space(1))) void*)ga,
                                       (__attribute__((address_space(3))) void*)(sAc + bs * 16384 + Loff),
                                       16, 0, 0);
    }
#pragma unroll
    for (int it = 0; it < 2; ++it) {              // sB: 64 rows
      int Loff = it * 4096 + wid * 1024;
      int L = Loff + lane * 16;
      int row = L >> 7;
      int csrc = ((L >> 4) & 7) ^ (row & 7);
      const unsigned short* gw = srcB0 + (size_t)row * K + k0 + csrc * 8;
      __builtin_amdgcn_global_load_lds((const __attribute__((address_space(1))) void*)gw,
                                       (__attribute__((address_space(3))) void*)(sBc + bs * 8192 + Loff),
                                       16, 0, 0);
    }
  };

  stage(0, 0);

  const int NT = K >> 6;
  for (int t = 0; t < NT; ++t) {
    const int cur = t & 1;
    __syncthreads();                 // drains tile t's loads; buf cur^1 reads done
    if (t + 1 < NT) stage(cur ^ 1, (t + 1) * 64);   // flies under compute(t)

#pragma unroll
    for (int ks = 0; ks < 2; ++ks) {
      bf16x8 af[4], bfr[2];
#pragma unroll
      for (int f = 0; f < 4; ++f) {
        int ra = wr * 64 + f * 16 + l15;
        af[f] = *(const bf16x8_a*)(sAc + cur * 16384 + ra * 128 +
                                   ((ks * 64 + q4 * 16) ^ ((ra & 7) << 4)));
      }
#pragma unroll
      for (int f = 0; f < 2; ++f) {
        int rb = wc * 32 + f * 16 + l15;
        bfr[f] = *(const bf16x8_a*)(sBc + cur * 8192 + rb * 128 +
                                    ((ks * 64 + q4 * 16) ^ ((rb & 7) << 4)));
      }
      __builtin_amdgcn_s_setprio(1);
#pragma unroll
      for (int i = 0; i < 4; ++i)
#pragma unroll
        for (int j = 0; j < 2; ++j)
          acc[i][j] = __builtin_amdgcn_mfma_f32_16x16x32_bf16(af[i], bfr[j], acc[i][j], 0, 0, 0);
      __builtin_amdgcn_s_setprio(0);
    }
  }

  if (MODE == 0 && blockIdx.z == 2) {
    // source-swapped: acc[i][j][r] = V^T value at
    //   n (W row / out col) = wt*128 + wr*64 + i*16 + q4*4 + r
    //   x row               = xt*64 + wc*32 + j*16 + l15
    const int bb = xt >> 1;                        // head slab index b*16+h
    const int sbase = (xt & 1) * 64;               // slab-row base (x row & 127)
#pragma unroll
    for (int i = 0; i < 4; ++i) {
      const int nb = wt * 128 + wr * 64 + i * 16 + q4 * 4;
#pragma unroll
      for (int j = 0; j < 2; ++j) {
        const int srow = sbase + wc * 32 + j * 16 + l15;
#pragma unroll
        for (int r = 0; r < 4; ++r) {
          const int n = nb + r;
          ob[(size_t)bb * 131072 + (size_t)(n & 63) * 2048 +
             (size_t)(n >> 6) * 128 + srow] = f2b(acc[i][j][r] + bias[n]);
        }
      }
    }
  } else {
#pragma unroll
    for (int i = 0; i < 4; ++i) {
      int row = (int)rowA0 + wr * 64 + i * 16 + q4 * 4;
#pragma unroll
      for (int j = 0; j < 2; ++j) {
        int col = (int)rowB0 + wc * 32 + j * 16 + l15;
        float bv = bias[col];
        if (MODE == 0 && blockIdx.z == 1) {
          // K, kv'-permuted: addr = bb*131072 + ((col>>6)*128 + (row&127))*64 + d
#pragma unroll
          for (int r = 0; r < 4; ++r) {
            size_t a = (size_t)((row + r) >> 7) * 131072 +
                       (size_t)(((col >> 6) << 7) + ((row + r) & 127)) * 64 + (col & 63);
            ob[a] = f2b(acc[i][j][r] + bv);
          }
        } else {
#pragma unroll
          for (int r = 0; r < 4; ++r) {
            float v = acc[i][j][r] + bv;
            if (MODE == 0) ob[(size_t)(row + r) * N + col] = f2b(v * 0.18033688f);  // Q: 0.125*log2e
            else           of[(size_t)(row + r) * N + col] = v;
          }
        }
      }
    }
  }
}

// Flash attention, swapped-QK^T, in-block split-K (R12/R14-verified geometry).
// Block = 512 thr (8 waves); waves [0,4) handle kv [0,1024), waves [4,8) handle
// [1024,2048). Each wave owns 32 q-rows (2 subtiles of 16). kv subtile = 32,
// dbuf K/VT in LDS, 1 barrier/iter. Flash-combine merge through LDS at the end.
// V and P LDS: 128B pair-packed rows (row i = two 64B logical rows 2i,2i+1),
// chunk ^= row&7 => 2-way bank access on all heavy reads (conflict-free, m136).
__global__ __launch_bounds__(512, 4) void attn_kernel(
    const unsigned short* __restrict__ Qg,
    const unsigned short* __restrict__ Kg,
    const unsigned short* __restrict__ VTg,
    unsigned short* __restrict__ ctx)
{
  const int tid = threadIdx.x;
  const int lane = tid & 63;
  const int wid = tid >> 6;          // 0..7
  const int half = wid >> 2;         // kv half
  const int wq = wid & 3;            // q-wave within half
  const int q4 = lane >> 4;
  const int l15 = lane & 15;

  // XCD-aware decode: xcd = bid&7 owns 4 whole heads -> K/VT L2-resident.
  const int bid = blockIdx.x;
  const int bh = (bid & 7) * 4 + ((bid >> 3) >> 4);
  const int qt = (bid >> 3) & 15;
  const int b = bh >> 4, h = bh & 15;
  const size_t base = (size_t)bh * 131072;
  const unsigned short* Qh = Qg + base;
  const unsigned short* Kh = Kg + base;
  const unsigned short* VTh = VTg + base;
  const int q0 = qt * 128;
  const int kvbase = half * 1024;

  __shared__ __align__(16) char smem[49152];
  char* sKc = smem;
  char* sVc = smem + 16384;
  char* sPw = smem + 32768 + wid * 2048;

  bf16x8 qf[2][2];
#pragma unroll
  for (int s = 0; s < 2; ++s)
#pragma unroll
    for (int ks = 0; ks < 2; ++ks)
      qf[s][ks] = *(const bf16x8*)(Qh + (size_t)(q0 + wq * 32 + s * 16 + l15) * 64 + ks * 32 + q4 * 8);

  const int u = tid & 255;                            // within-half thread index
  const int rK = u >> 3;                              // 0..31 kv row
  const int cK = ((u & 7) ^ (rK & 7)) * 8;
  const unsigned short* gK = Kh + (size_t)(kvbase + rK) * 64 + cK;
  const int rV = u >> 3;                              // 0..31 LDS row
  const int cV = (u & 7) ^ (rV & 7);                  // logical chunk
  const int dV = rV * 2 + (cV >> 2);
  const unsigned short* gV = VTh + (size_t)dV * 2048 + kvbase + (cV & 3) * 8;

  auto stage = [&](int bs, int t) {                   // t = tile idx within half
    char* dK = sKc + half * 8192 + bs * 4096 + wq * 1024;
    char* dV_ = sVc + half * 8192 + bs * 4096 + wq * 1024;
    __builtin_amdgcn_global_load_lds(
        (const __attribute__((address_space(1))) void*)(gK + (size_t)t * 2048),
        (__attribute__((address_space(3))) void*)dK, 16, 0, 0);
    __builtin_amdgcn_global_load_lds(
        (const __attribute__((address_space(1))) void*)(gV + t * 32),
        (__attribute__((address_space(3))) void*)dV_, 16, 0, 0);
  };

  const int vp_chunk = (((l15 & 1) * 4 + q4) ^ ((l15 >> 1) & 7)) * 16;
  const int vp_row = (l15 >> 1) * 128;

  f32x4 oacc[2][4];                    // O[s][q=q4*4+r][d=fn*16+l15]
#pragma unroll
  for (int s = 0; s < 2; ++s)
#pragma unroll
    for (int fn = 0; fn < 4; ++fn) oacc[s][fn] = (f32x4){0.f, 0.f, 0.f, 0.f};
  float m_run[2] = {-INFINITY, -INFINITY};   // log2-domain state for q-row = l15
  float l_run[2] = {0.f, 0.f};

  stage(0, 0);

  for (int t = 0; t < 32; ++t) {
    const int cur = t & 1;
    __syncthreads();                   // drains vmcnt: tile t staged; buf cur^1 free
    if (t < 31) stage(cur ^ 1, t + 1);

    char* kbuf = sKc + half * 8192 + cur * 4096;
    char* vbuf = sVc + half * 8192 + cur * 4096;

    // ---- S^T = K Q^T : sc[s][fm][r] = S_log2[kv=fm*16+q4*4+r][q(s)=l15]
    f32x4 sc[2][2];
#pragma unroll
    for (int s = 0; s < 2; ++s)
#pragma unroll
      for (int fm = 0; fm < 2; ++fm) sc[s][fm] = (f32x4){0.f, 0.f, 0.f, 0.f};
    __builtin_amdgcn_s_setprio(1);
#pragma unroll
    for (int ks = 0; ks < 2; ++ks) {
#pragma unroll
      for (int fm = 0; fm < 2; ++fm) {
        const int rk = fm * 16 + l15;
        bf16x8_a kf = *(const bf16x8_a*)(kbuf + rk * 128 +
                                         ((ks * 64 + q4 * 16) ^ ((rk & 7) << 4)));
        sc[0][fm] = __builtin_amdgcn_mfma_f32_16x16x32_bf16(kf, qf[0][ks], sc[0][fm], 0, 0, 0);
        sc[1][fm] = __builtin_amdgcn_mfma_f32_16x16x32_bf16(kf, qf[1][ks], sc[1][fm], 0, 0, 0);
      }
    }
    __builtin_amdgcn_s_setprio(0);

    // ---- online softmax per subtile (exp2 domain, defer-max); 8 vals/lane
#pragma unroll
    for (int s = 0; s < 2; ++s) {
      float mx = fmaxf(fmaxf(fmaxf(sc[s][0][0], sc[s][0][1]), fmaxf(sc[s][0][2], sc[s][0][3])),
                       fmaxf(fmaxf(sc[s][1][0], sc[s][1][1]), fmaxf(sc[s][1][2], sc[s][1][3])));
      mx = fmaxf(mx, __shfl_xor(mx, 16));
      mx = fmaxf(mx, __shfl_xor(mx, 32));
      if (!__all(mx <= m_run[s] + 11.54f)) {   // wave-uniform rescale path
        const float mnew = fmaxf(m_run[s], mx);
        const float sc_o = __builtin_amdgcn_exp2f(m_run[s] - mnew);  // -inf on t=0 -> 0
        l_run[s] *= sc_o;
        m_run[s] = mnew;
#pragma unroll
        for (int r = 0; r < 4; ++r) {
          const float so = __shfl(sc_o, (lane & 48) | (q4 * 4 + r));
#pragma unroll
          for (int fn = 0; fn < 4; ++fn) oacc[s][fn][r] *= so;
        }
      }
      float rs = 0.f;
#pragma unroll
      for (int fm = 0; fm < 2; ++fm)
#pragma unroll
        for (int r = 0; r < 4; ++r) {
          sc[s][fm][r] = __builtin_amdgcn_exp2f(sc[s][fm][r] - m_run[s]);  // <= 2^11.54
          rs += sc[s][fm][r];
        }
      rs += __shfl_xor(rs, 16);
      rs += __shfl_xor(rs, 32);
      l_run[s] += rs;

      // pack P -> pair-packed sP: q=s*16+l15 -> row (s*8+(l15>>1)), 128B rows;
      // logical chunk = (q&1)*4 + fm*2 + (q4>>1), stored chunk ^= row&7.
      char* rowp = sPw + (s * 8 + (l15 >> 1)) * 128;
      const int wbase = ((l15 & 1) * 4 + (q4 >> 1)) ^ ((l15 >> 1) & 7);
#pragma unroll
      for (int fm = 0; fm < 2; ++fm) {
        u32x2 pk;
        pk[0] = cvtpk_bf16(sc[s][fm][0], sc[s][fm][1]);
        pk[1] = cvtpk_bf16(sc[s][fm][2], sc[s][fm][3]);
        *(u32x2_a*)(rowp + ((wbase ^ (fm * 2)) << 4) + (q4 & 1) * 8) = pk;
      }
    }
    // fence: cross-lane LDS exchange within the wave (writes above, reads below)
    asm volatile("s_waitcnt lgkmcnt(0)" ::: "memory");
    __builtin_amdgcn_sched_barrier(0);

    // ---- O += P V : A from sP, B = VT rows; both pair-packed (2-way banks)
    bf16x8 pf[2];
#pragma unroll
    for (int s = 0; s < 2; ++s)
      pf[s] = *(const bf16x8_a*)(sPw + s * 1024 + vp_row + vp_chunk);
    __builtin_amdgcn_s_setprio(1);
#pragma unroll
    for (int fn = 0; fn < 4; ++fn) {
      bf16x8_a vf = *(const bf16x8_a*)(vbuf + fn * 1024 + vp_row + vp_chunk);
      oacc[0][fn] = __builtin_amdgcn_mfma_f32_16x16x32_bf16(pf[0], vf, oacc[0][fn], 0, 0, 0);
      oacc[1][fn] = __builtin_amdgcn_mfma_f32_16x16x32_bf16(pf[1], vf, oacc[1][fn], 0, 0, 0);
    }
    __builtin_amdgcn_s_setprio(0);
  }

  // ---- split-K merge: half 1 dumps O/m/l; half 0 flash-combines + stores
  __syncthreads();                     // all compute done; smem reusable
  if (half == 1) {
    char* mb = smem + wq * 8192;
#pragma unroll
    for (int s = 0; s < 2; ++s)
#pragma unroll
      for (int fn = 0; fn < 4; ++fn)
        *(f32x4_a*)(mb + (((s * 4 + fn) * 64) + lane) * 16) = oacc[s][fn];
    if (q4 == 0) {
#pragma unroll
      for (int s = 0; s < 2; ++s)
        *(float2*)(smem + 32768 + ((wq * 2 + s) * 16 + l15) * 8) =
            make_float2(m_run[s], l_run[s]);
    }
  }
  __syncthreads();
  if (half == 0) {
    char* mb = smem + wq * 8192;
#pragma unroll
    for (int s = 0; s < 2; ++s) {
      float2 ml = *(const float2*)(smem + 32768 + ((wq * 2 + s) * 16 + l15) * 8);
      const float mm = fmaxf(m_run[s], ml.x);
      const float w1 = __builtin_amdgcn_exp2f(m_run[s] - mm);
      const float w2 = __builtin_amdgcn_exp2f(ml.x - mm);
      const float li = 1.0f / (l_run[s] * w1 + ml.y * w2);
#pragma unroll
      for (int r = 0; r < 4; ++r) {
        const int src = (lane & 48) | (q4 * 4 + r);
        const float w1b = __shfl(w1, src);
        const float w2b = __shfl(w2, src);
        const float lib = __shfl(li, src);
        const int trow = q0 + wq * 32 + s * 16 + q4 * 4 + r;
        const size_t ro = ((size_t)b * 2048 + trow) * 1024 + h * 64;
#pragma unroll
        for (int fn = 0; fn < 4; ++fn) {
          f32x4 o2 = *(const f32x4_a*)(mb + (((s * 4 + fn) * 64) + lane) * 16);
          ctx[ro + fn * 16 + l15] = f2b((oacc[s][fn][r] * w1b + o2[r] * w2b) * lib);
        }
      }
    }
  }
}

extern "C" void kernel_launch(void* const* d_in, const int* in_sizes, int n_in,
                              void* d_out, int out_size, void* d_ws, size_t ws_size,
                              hipStream_t stream) {
  const float* x  = (const float*)d_in[0];
  const float* wq = (const float*)d_in[1];
  const float* bq = (const float*)d_in[2];
  const float* wk = (const float*)d_in[3];
  const float* bk = (const float*)d_in[4];
  const float* wv = (const float*)d_in[5];
  const float* bv = (const float*)d_in[6];
  const float* wo = (const float*)d_in[7];
  const float* bo = (const float*)d_in[8];
  // d_in[9]/d_in[10] (rot tables) unused: constant-angle RoPE cancels in q.k^T.

  char* ws = (char*)d_ws;
  unsigned short* xb  = (unsigned short*)(ws);               // 8 MB (reused as ctx)
  unsigned short* wqb = (unsigned short*)(ws + 8388608);
  unsigned short* wkb = (unsigned short*)(ws + 10485760);
  unsigned short* wvb = (unsigned short*)(ws + 12582912);
  unsigned short* wob = (unsigned short*)(ws + 14680064);
  unsigned short* Qb  = (unsigned short*)(ws + 16777216);    // 8 MB
  unsigned short* Kb  = (unsigned short*)(ws + 25165824);    // 8 MB, kv'-permuted
  unsigned short* VTb = (unsigned short*)(ws + 33554432);    // 8 MB, [bh][d][kv']
  unsigned short* ctx = xb;  // x dead after QKV projection

  cvt_all<<<8192, 256, 0, stream>>>(x, wq, wk, wv, wo, xb, wqb, wkb, wvb, wob);

  gemm_bt<0><<<dim3(32, 16, 3), 256, 0, stream>>>(
      xb, wqb, wkb, wvb, bq, bk, bv, Qb, Kb, VTb, nullptr, 4096, 1024, 1024);

  attn_kernel<<<dim3(512), dim3(512), 0, stream>>>(Qb, Kb, VTb, ctx);

  gemm_bt<1><<<dim3(32, 16, 1), 256, 0, stream>>>(
      ctx, wob, nullptr, nullptr, bo, nullptr, nullptr, nullptr, nullptr, nullptr,
      (float*)d_out, 4096, 1024, 1024);
}